// Round 3
// baseline (90.143 us; speedup 1.0000x reference)
//
#include <hip/hip_runtime.h>

// out[b,o] = x@W1 + x^T W2[:,:,o] x + bias
// Quadratic via GEMM T = X(512x784) @ W2v(784x7840) fused with
// quad[b,o] = sum_j x[b,j] * T[b, j*10+o].
// GEMM structure: block = 64x160 tile, FULL K in LDS (A panel, padded rows),
// 5 waves x (4 Mfrag x 2 Nfrag), B read contiguously from a pre-tiled layout
// Wt2[bx][kk][160][32] straight into registers. ZERO in-loop barriers.

#define D_IN 784
#define N_COL 7840
#define KP 832          // K padded (26 * 32)
#define M_B 512
#define OUTN 10
#define BM 64
#define BN 160
#define NBX 49          // N_COL / BN
#define NKK 26          // KP / 32
#define LDSA 1680       // A row stride bytes: 832*2 + 16 pad (bank-quad shift 4)
#define WS_NEED ((size_t)2 * ((size_t)M_B * KP + (size_t)N_COL * KP) + (size_t)NBX * M_B * OUTN * 4)

typedef __attribute__((ext_vector_type(4))) float f32x4;
typedef __attribute__((ext_vector_type(8))) __bf16 bf16x8;

__device__ __forceinline__ unsigned short f2bf(float f) {
  unsigned u = __builtin_bit_cast(unsigned, f);
  u += 0x7FFFu + ((u >> 16) & 1u);
  return (unsigned short)(u >> 16);
}

// ---- prep: x (512x784 f32) -> xb (512x832 bf16, zero-padded K) ----
__global__ __launch_bounds__(256) void conv_x_kernel(const float* __restrict__ x,
                                                     unsigned short* __restrict__ xb) {
  int t = blockIdx.x * 256 + threadIdx.x;
  int b = t / 208;
  int c4 = (t - b * 208) * 4;
  ushort4 u;
  u.x = (c4 + 0 < D_IN) ? f2bf(x[(size_t)b * D_IN + c4 + 0]) : (unsigned short)0;
  u.y = (c4 + 1 < D_IN) ? f2bf(x[(size_t)b * D_IN + c4 + 1]) : (unsigned short)0;
  u.z = (c4 + 2 < D_IN) ? f2bf(x[(size_t)b * D_IN + c4 + 2]) : (unsigned short)0;
  u.w = (c4 + 3 < D_IN) ? f2bf(x[(size_t)b * D_IN + c4 + 3]) : (unsigned short)0;
  *(ushort4*)(xb + (size_t)b * KP + c4) = u;
}

// ---- prep: W2v (784x7840 f32) -> Wt2 tiled bf16: [bx][kk][c:160][ko:32] ----
// element (k, gc) -> Wt2[(((gc/160)*NKK + k/32)*160 + gc%160)*32 + k%32]
__global__ __launch_bounds__(256) void transpose_w_kernel(const float* __restrict__ W2v,
                                                          unsigned short* __restrict__ Wt2) {
  __shared__ float tile[32][33];
  int c0 = blockIdx.x * 32;                   // 245 col-tiles (never cross 160-boundary)
  int k0 = blockIdx.y * 32;                   // 26 k-tiles
  int tx = threadIdx.x;                       // 32
  int ty = threadIdx.y;                       // 8
#pragma unroll
  for (int q = 0; q < 4; ++q) {
    int k = k0 + ty + 8 * q;
    tile[ty + 8 * q][tx] = (k < D_IN) ? W2v[(size_t)k * N_COL + (c0 + tx)] : 0.f;
  }
  __syncthreads();
  int bxg = c0 / BN;
  int cl0 = c0 - bxg * BN;
  unsigned short* dst = Wt2 + (((size_t)bxg * NKK + blockIdx.y) * BN + cl0) * 32;
#pragma unroll
  for (int q = 0; q < 4; ++q) {
    int cy = ty + 8 * q;
    dst[cy * 32 + tx] = f2bf(tile[tx][cy]);   // consecutive tx -> contiguous 64B
  }
}

// ---- linear part + bias: out[b,:] = x[b,:] @ W1 + bias ----
__global__ __launch_bounds__(256) void init_out_kernel(const float* __restrict__ x,
                                                       const float* __restrict__ W,
                                                       const float* __restrict__ bias,
                                                       float* __restrict__ out) {
  int b = blockIdx.x;
  int t = threadIdx.x;
  __shared__ float part[OUTN];
  if (t < OUTN) part[t] = bias[t];
  __syncthreads();
  float acc[OUTN];
#pragma unroll
  for (int o = 0; o < OUTN; ++o) acc[o] = 0.f;
  for (int i = t; i < D_IN; i += 256) {
    float xv = x[(size_t)b * D_IN + i];
#pragma unroll
    for (int o = 0; o < OUTN; ++o) acc[o] += xv * W[i * OUTN + o];
  }
#pragma unroll
  for (int o = 0; o < OUTN; ++o) {
    float v = acc[o];
#pragma unroll
    for (int s = 32; s > 0; s >>= 1) v += __shfl_down(v, s);
    if ((t & 63) == 0) atomicAdd(&part[o], v);
  }
  __syncthreads();
  if (t < OUTN) out[(size_t)b * OUTN + t] = part[t];
}

// ---- main GEMM + fused quad epilogue (barrier-free K loop) ----
template <int USE_WS>
__global__ __launch_bounds__(320, 1) void gemm_quad_kernel(const unsigned short* __restrict__ xb,
                                                           const unsigned short* __restrict__ Wt2,
                                                           const float* __restrict__ x,
                                                           float* __restrict__ dst) {
  __shared__ char As[BM * LDSA];              // 105 KB padded A panel
  __shared__ float xs[BM * 16];               // x[64 rows][16 j-cols of this block]
  const int tid = threadIdx.x;                // 320
  const int w = tid >> 6, l = tid & 63, lr = l & 15, lh = l >> 4;
  const int bn0 = blockIdx.x * BN;
  const int bm0 = blockIdx.y * BM;
  const int j00 = blockIdx.x * 16;            // 160 cols == j in [16bx,16bx+16), o=0..9

  // stage A panel: contiguous 104 KB read (rows bm0..bm0+63 of xb)
  {
    const unsigned short* src = xb + (size_t)bm0 * KP;
    for (int i = tid; i < BM * 104; i += 320) {
      int r = i / 104, c = i - r * 104;
      *(uint4*)(As + r * LDSA + c * 16) = *(const uint4*)(src + (size_t)i * 8);
    }
  }
  for (int i = tid; i < BM * 16; i += 320) {
    int r = i >> 4, jj = i & 15;
    xs[i] = x[(size_t)(bm0 + r) * D_IN + j00 + jj];
  }
  __syncthreads();

  f32x4 acc[4][2];
#pragma unroll
  for (int mf = 0; mf < 4; ++mf)
#pragma unroll
    for (int n = 0; n < 2; ++n) acc[mf][n] = (f32x4){0.f, 0.f, 0.f, 0.f};

  // B: contiguous tiled layout; per kk this block reads one 10 KB chunk.
  const unsigned short* bsrc = Wt2 + ((size_t)blockIdx.x * NKK * BN) * 32
                             + (w * 32 + lr) * 32 + lh * 8;
  const char* abase = As + lh * 16 + lr * LDSA;

#pragma unroll
  for (int kk = 0; kk < NKK; ++kk) {
    bf16x8 b0 = *(const bf16x8*)(bsrc + (size_t)kk * (BN * 32));
    bf16x8 b1 = *(const bf16x8*)(bsrc + (size_t)kk * (BN * 32) + 16 * 32);
    bf16x8 a[4];
#pragma unroll
    for (int mf = 0; mf < 4; ++mf)
      a[mf] = *(const bf16x8*)(abase + mf * (16 * LDSA) + kk * 64);
#pragma unroll
    for (int mf = 0; mf < 4; ++mf) {
      acc[mf][0] = __builtin_amdgcn_mfma_f32_16x16x32_bf16(a[mf], b0, acc[mf][0], 0, 0, 0);
      acc[mf][1] = __builtin_amdgcn_mfma_f32_16x16x32_bf16(a[mf], b1, acc[mf][1], 0, 0, 0);
    }
  }

  // epilogue: quad partial for this block's 160 cols
  __syncthreads();
  float* part = (float*)As;                   // [64][10], aliases A (post-barrier)
  for (int i = tid; i < BM * OUTN; i += 320) part[i] = 0.f;
  __syncthreads();
#pragma unroll
  for (int n = 0; n < 2; ++n) {
    int gc = bn0 + w * 32 + n * 16 + lr;
    int j = gc / 10, o = gc - j * 10;
    int jj = j - j00;
#pragma unroll
    for (int mf = 0; mf < 4; ++mf)
#pragma unroll
      for (int r = 0; r < 4; ++r) {
        int rr = mf * 16 + lh * 4 + r;        // C/D: col=lane&15, row=(lane>>4)*4+reg
        atomicAdd(&part[rr * OUTN + o], acc[mf][n][r] * xs[rr * 16 + jj]);
      }
  }
  __syncthreads();
  if (USE_WS) {
    float* wp = dst + (size_t)blockIdx.x * (M_B * OUTN) + bm0 * OUTN;
    for (int i = tid; i < BM * OUTN; i += 320) wp[i] = part[i];
  } else {
    for (int i = tid; i < BM * OUTN; i += 320) atomicAdd(&dst[bm0 * OUTN + i], part[i]);
  }
}

// ---- sum the 49 per-colblock partials into out ----
__global__ __launch_bounds__(256) void reduce_kernel(const float* __restrict__ ws,
                                                     float* __restrict__ out) {
  int i = blockIdx.x * 256 + threadIdx.x;
  if (i < M_B * OUTN) {
    float s = 0.f;
    for (int c = 0; c < NBX; ++c) s += ws[(size_t)c * (M_B * OUTN) + i];
    out[i] += s;
  }
}

extern "C" void kernel_launch(void* const* d_in, const int* in_sizes, int n_in,
                              void* d_out, int out_size, void* d_ws, size_t ws_size,
                              hipStream_t stream) {
  const float* x = (const float*)d_in[0];
  const float* W = (const float*)d_in[1];
  const float* bias = (const float*)d_in[2];
  float* out = (float*)d_out;

  unsigned short* xb = (unsigned short*)d_ws;            // 512*832 bf16
  unsigned short* Wt2 = xb + (size_t)M_B * KP;           // 7840*832 bf16 (tiled layout)
  float* wsp = (float*)(Wt2 + (size_t)N_COL * KP);       // 49*512*10 f32 partials

  conv_x_kernel<<<(M_B * (KP / 4)) / 256, 256, 0, stream>>>(x, xb);
  transpose_w_kernel<<<dim3(N_COL / 32, KP / 32), dim3(32, 8), 0, stream>>>(W + D_IN * OUTN, Wt2);
  init_out_kernel<<<M_B, 256, 0, stream>>>(x, W, bias, out);

  if (ws_size >= WS_NEED) {
    gemm_quad_kernel<1><<<dim3(NBX, M_B / BM), 320, 0, stream>>>(xb, Wt2, x, wsp);
    reduce_kernel<<<(M_B * OUTN + 255) / 256, 256, 0, stream>>>(wsp, out);
  } else {
    gemm_quad_kernel<0><<<dim3(NBX, M_B / BM), 320, 0, stream>>>(xb, Wt2, x, out);
  }
}

// Round 4
// 84.046 us; speedup vs baseline: 1.0725x; 1.0725x over previous
//
#include <hip/hip_runtime.h>

// out[b,o] = x@W1 + x^T W2[:,:,o] x + bias
// Quadratic via GEMM T = X(512x784) @ W2v(784x7840) fused with
// quad[b,o] = sum_j x[b,j] * T[b, j*10+o].
// Key structure: BM=512 (full M in one block) so each W element is read by
// EXACTLY ONE block -> f32->bf16 conversion fused into the GEMM (no transpose
// pass, W streamed once: ~25 MB total HBM). Grid 245 blocks x 512 thr.
// Raw-barrier (no vmcnt drain) K-loop, W-slices prefetched 2 steps ahead.

#define D_IN 784
#define NC 7840
#define KP 832          // 13 * 64
#define MB 512
#define OUTN 10
#define BN 32
#define NBX 245         // NC / BN
#define NKT 13          // KP / 64

typedef __attribute__((ext_vector_type(4))) float f32x4;
typedef __attribute__((ext_vector_type(8))) __bf16 bf16x8;

__device__ __forceinline__ unsigned short f2bf(float f) {
  unsigned u = __builtin_bit_cast(unsigned, f);
  u += 0x7FFFu + ((u >> 16) & 1u);
  return (unsigned short)(u >> 16);
}

#define RAWBAR() do { asm volatile("s_waitcnt lgkmcnt(0)" ::: "memory"); \
  __builtin_amdgcn_s_barrier(); __builtin_amdgcn_sched_barrier(0); } while (0)

// ---- prep: x (512x784 f32) -> xb (512x832 bf16, zero-padded K) ----
__global__ __launch_bounds__(256) void conv_x_kernel(const float* __restrict__ x,
                                                     unsigned short* __restrict__ xb) {
  int t = blockIdx.x * 256 + threadIdx.x;
  int b = t / 208;
  int c4 = (t - b * 208) * 4;
  ushort4 u;
  u.x = (c4 + 0 < D_IN) ? f2bf(x[(size_t)b * D_IN + c4 + 0]) : (unsigned short)0;
  u.y = (c4 + 1 < D_IN) ? f2bf(x[(size_t)b * D_IN + c4 + 1]) : (unsigned short)0;
  u.z = (c4 + 2 < D_IN) ? f2bf(x[(size_t)b * D_IN + c4 + 2]) : (unsigned short)0;
  u.w = (c4 + 3 < D_IN) ? f2bf(x[(size_t)b * D_IN + c4 + 3]) : (unsigned short)0;
  *(ushort4*)(xb + (size_t)b * KP + c4) = u;
}

// ---- linear part + bias: out[b,:] = x[b,:] @ W1 + bias ----
__global__ __launch_bounds__(256) void init_out_kernel(const float* __restrict__ x,
                                                       const float* __restrict__ W,
                                                       const float* __restrict__ bias,
                                                       float* __restrict__ out) {
  int b = blockIdx.x;
  int t = threadIdx.x;
  __shared__ float part[OUTN];
  if (t < OUTN) part[t] = bias[t];
  __syncthreads();
  float acc[OUTN];
#pragma unroll
  for (int o = 0; o < OUTN; ++o) acc[o] = 0.f;
  for (int i = t; i < D_IN; i += 256) {
    float xv = x[(size_t)b * D_IN + i];
#pragma unroll
    for (int o = 0; o < OUTN; ++o) acc[o] += xv * W[i * OUTN + o];
  }
#pragma unroll
  for (int o = 0; o < OUTN; ++o) {
    float v = acc[o];
#pragma unroll
    for (int s = 32; s > 0; s >>= 1) v += __shfl_down(v, s);
    if ((t & 63) == 0) atomicAdd(&part[o], v);
  }
  __syncthreads();
  if (t < OUTN) out[(size_t)b * OUTN + t] = part[t];
}

// ---- main: full-M GEMM with fused W conversion + fused quad epilogue ----
template <int USE_WS>
__global__ __launch_bounds__(512, 2) void gemm_quad_kernel(const unsigned short* __restrict__ xb,
                                                           const float* __restrict__ W2v,
                                                           const float* __restrict__ x,
                                                           float* __restrict__ dst) {
  __shared__ float tile[64 * 33];             // f32 staging of one 64k x 32col W slice
  __shared__ char Bs[2][4096];                // bf16 [col][k] swizzled, double-buffered
  __shared__ float xs[MB * 5];                // x cols j0..j0+4 for all 512 rows
  __shared__ float part[MB * OUTN];           // quad partials
  const int tid = threadIdx.x;
  const int w = tid >> 6, l = tid & 63, lr = l & 15, lh = l >> 4;
  const int bn0 = blockIdx.x * BN;
  const int j0 = bn0 / 10;

  // xs staging (read only in epilogue)
  for (int i = tid; i < MB * 5; i += 512) {
    int r = i / 5, jj = i - r * 5;
    int j = j0 + jj;
    xs[i] = (j < D_IN) ? x[(size_t)r * D_IN + j] : 0.f;
  }

  // per-thread W-slice unit: row (k within step) 0..63, col-group 0..7
  const int srow = tid >> 3, scg = tid & 7;
  const int ccol = tid >> 4, ckc = (tid >> 1) & 7, ch = tid & 1;  // cvt unit

  f32x4 acc[4][2];
#pragma unroll
  for (int mf = 0; mf < 4; ++mf)
#pragma unroll
    for (int n = 0; n < 2; ++n) acc[mf][n] = (f32x4){0.f, 0.f, 0.f, 0.f};

  // load W f32 slice for K-step kt into registers
  auto loadslice = [&](int kt) -> f32x4 {
    int k = kt * 64 + srow;
    if (k < D_IN) return *(const f32x4*)(W2v + (size_t)k * NC + bn0 + scg * 4);
    return (f32x4){0.f, 0.f, 0.f, 0.f};
  };
  auto writetile = [&](f32x4 v) {             // scalar stores: 4B-aligned, ~2-way banks
    tile[srow * 33 + scg * 4 + 0] = v[0];
    tile[srow * 33 + scg * 4 + 1] = v[1];
    tile[srow * 33 + scg * 4 + 2] = v[2];
    tile[srow * 33 + scg * 4 + 3] = v[3];
  };
  auto cvt_to = [&](char* bs) {               // transpose-read tile, write bf16 [col][k]
    int kb = ckc * 8 + ch * 4;
    unsigned int p0 = f2bf(tile[(kb + 0) * 33 + ccol]) |
                      ((unsigned)f2bf(tile[(kb + 1) * 33 + ccol]) << 16);
    unsigned int p1 = f2bf(tile[(kb + 2) * 33 + ccol]) |
                      ((unsigned)f2bf(tile[(kb + 3) * 33 + ccol]) << 16);
    uint2 p; p.x = p0; p.y = p1;
    *(uint2*)(bs + ccol * 128 + ((ckc ^ (ccol & 7)) << 4) + ch * 8) = p;
  };

  // prologue
  f32x4 rA = loadslice(0);
  f32x4 rB = loadslice(1);
  writetile(rA);
  __syncthreads();
  cvt_to(Bs[0]);
  __syncthreads();

  // A-frag base addrs (per mf), kt offsets fold into immediates after unroll
  const unsigned short* abase[4];
#pragma unroll
  for (int mf = 0; mf < 4; ++mf)
    abase[mf] = xb + (size_t)(w * 64 + mf * 16 + lr) * KP + lh * 8;

#pragma unroll
  for (int kt = 0; kt < NKT; ++kt) {
    const int cur = kt & 1, nxt = cur ^ 1;
    // P1: refill consumed reg set (kt+2), write next slice (kt+1) to f32 tile
    if (kt + 2 < NKT) {
      if (cur == 0) rA = loadslice(kt + 2); else rB = loadslice(kt + 2);
    }
    if (kt + 1 < NKT) writetile(cur == 0 ? rB : rA);
    // A-frags for this step (global, L2-hot)
    bf16x8 a[4][2];
#pragma unroll
    for (int mf = 0; mf < 4; ++mf)
#pragma unroll
      for (int kk = 0; kk < 2; ++kk)
        a[mf][kk] = *(const bf16x8*)(abase[mf] + kt * 64 + kk * 32);
    RAWBAR();
    // P2: convert next slice, read b-frags, MFMA
    if (kt + 1 < NKT) cvt_to(Bs[nxt]);
    const char* bsc = Bs[cur];
    bf16x8 bf[2][2];
#pragma unroll
    for (int kk = 0; kk < 2; ++kk)
#pragma unroll
      for (int n = 0; n < 2; ++n) {
        int col = n * 16 + lr;
        int kcf = kk * 4 + lh;
        bf[kk][n] = *(const bf16x8*)(bsc + col * 128 + ((kcf ^ (col & 7)) << 4));
      }
#pragma unroll
    for (int kk = 0; kk < 2; ++kk)
#pragma unroll
      for (int mf = 0; mf < 4; ++mf)
#pragma unroll
        for (int n = 0; n < 2; ++n)
          acc[mf][n] = __builtin_amdgcn_mfma_f32_16x16x32_bf16(a[mf][kk], bf[kk][n],
                                                               acc[mf][n], 0, 0, 0);
    RAWBAR();
  }

  // epilogue: quad partials over this block's 32 cols
  __syncthreads();
  for (int i = tid; i < MB * OUTN; i += 512) part[i] = 0.f;
  __syncthreads();
#pragma unroll
  for (int n = 0; n < 2; ++n) {
    int gc = bn0 + n * 16 + lr;
    int j = gc / 10, o = gc - j * 10;
    int jj = j - j0;
#pragma unroll
    for (int mf = 0; mf < 4; ++mf)
#pragma unroll
      for (int r = 0; r < 4; ++r) {
        int rr = w * 64 + mf * 16 + lh * 4 + r;  // C/D: col=lane&15, row=(lane>>4)*4+reg
        atomicAdd(&part[rr * OUTN + o], acc[mf][n][r] * xs[rr * 5 + jj]);
      }
  }
  __syncthreads();
  if (USE_WS) {
    float* wp = dst + (size_t)blockIdx.x * (MB * OUTN);
    for (int i = tid; i < MB * OUTN; i += 512) wp[i] = part[i];
  } else {
    for (int i = tid; i < MB * OUTN; i += 512) atomicAdd(&dst[i], part[i]);
  }
}

// ---- sum the 245 per-colblock partials into out ----
__global__ __launch_bounds__(256) void reduce_kernel(const float* __restrict__ ws,
                                                     float* __restrict__ out) {
  int i = blockIdx.x * 256 + threadIdx.x;     // 5120
  if (i < MB * OUTN) {
    float s0 = 0.f, s1 = 0.f, s2 = 0.f, s3 = 0.f;
    int c = 0;
    for (; c + 4 <= NBX; c += 4) {
      s0 += ws[(size_t)(c + 0) * (MB * OUTN) + i];
      s1 += ws[(size_t)(c + 1) * (MB * OUTN) + i];
      s2 += ws[(size_t)(c + 2) * (MB * OUTN) + i];
      s3 += ws[(size_t)(c + 3) * (MB * OUTN) + i];
    }
    for (; c < NBX; ++c) s0 += ws[(size_t)c * (MB * OUTN) + i];
    out[i] += (s0 + s1) + (s2 + s3);
  }
}

extern "C" void kernel_launch(void* const* d_in, const int* in_sizes, int n_in,
                              void* d_out, int out_size, void* d_ws, size_t ws_size,
                              hipStream_t stream) {
  const float* x = (const float*)d_in[0];
  const float* W = (const float*)d_in[1];
  const float* bias = (const float*)d_in[2];
  float* out = (float*)d_out;

  unsigned short* xb = (unsigned short*)d_ws;               // 512*832 bf16 = 852 KB
  float* wsp = (float*)((char*)d_ws + (size_t)MB * KP * 2); // 245*5120 f32 = 5 MB
  const size_t ws_need = (size_t)MB * KP * 2 + (size_t)NBX * MB * OUTN * 4;

  conv_x_kernel<<<(MB * (KP / 4)) / 256, 256, 0, stream>>>(x, xb);
  init_out_kernel<<<MB, 256, 0, stream>>>(x, W, bias, out);

  if (ws_size >= ws_need) {
    gemm_quad_kernel<1><<<NBX, 512, 0, stream>>>(xb, W + D_IN * OUTN, x, wsp);
    reduce_kernel<<<(MB * OUTN + 255) / 256, 256, 0, stream>>>(wsp, out);
  } else {
    gemm_quad_kernel<0><<<NBX, 512, 0, stream>>>(xb, W + D_IN * OUTN, x, out);
  }
}

// Round 5
// 78.829 us; speedup vs baseline: 1.1435x; 1.0662x over previous
//
#include <hip/hip_runtime.h>

// out[b,o] = x@W1 + quad + bias,  quad[b,o] = sum_ij x[b,i] x[b,j] W2[i,j,o].
// Reformulated: quad = Z @ W2v' where Z[b, i*784+j] = x[b,i]*x[b,j] (computed
// on the fly, never materialized) and W2v'[(i,j), o] = W[7840 + (i*784+j)*10 + o]
// -- W's NATIVE layout is already the B matrix. No transpose pass, no T matrix.
// Block: full M=512, i-slab of 4, j in 25 windows of 32. K-step = 32 (one MFMA
// per m-frag). B prefetched 4 steps deep in regs; x-window + B double-buffered
// in LDS; per-step barrier is raw lgkmcnt(0)+s_barrier (vmcnt NEVER drained).

#define D_IN 784
#define JP 800           // j padded to 25*32
#define MB 512
#define OUTN 10
#define NJW 25
#define ISLAB 4
#define NBLK 196         // 784 / ISLAB
typedef unsigned short ushort_t;
typedef unsigned int uint_t;

typedef __attribute__((ext_vector_type(4))) float f32x4;
typedef __attribute__((ext_vector_type(8))) __bf16 bf16x8;

__device__ __forceinline__ ushort_t f2bf(float f) {
  uint_t u = __builtin_bit_cast(uint_t, f);
  u += 0x7FFFu + ((u >> 16) & 1u);
  return (ushort_t)(u >> 16);
}
__device__ __forceinline__ float bfu_lo(uint_t v) {  // low bf16 of packed pair
  return __builtin_bit_cast(float, v << 16);
}
__device__ __forceinline__ float bfu_hi(uint_t v) {  // high bf16 of packed pair
  return __builtin_bit_cast(float, v & 0xFFFF0000u);
}

#define RAWBAR() do { asm volatile("s_waitcnt lgkmcnt(0)" ::: "memory"); \
  __builtin_amdgcn_s_barrier(); __builtin_amdgcn_sched_barrier(0); } while (0)

// ---- prep: x f32 [512][784] -> xb bf16 [512][800] (row-major, j-padded)
//                               and xT bf16 [784][512] (transposed) ----
__global__ __launch_bounds__(256) void prep_kernel(const float* __restrict__ x,
                                                   ushort_t* __restrict__ xb,
                                                   ushort_t* __restrict__ xT) {
  __shared__ float tile[32][33];
  const int j0 = blockIdx.x * 32;             // 25 j-tiles (covers 800)
  const int b0 = blockIdx.y * 32;             // 16 b-tiles
  const int tx = threadIdx.x, ty = threadIdx.y;
#pragma unroll
  for (int q = 0; q < 4; ++q) {
    int b = b0 + ty + 8 * q;
    int j = j0 + tx;
    float v = (j < D_IN) ? x[(size_t)b * D_IN + j] : 0.f;
    xb[(size_t)b * JP + j] = f2bf(v);
    tile[ty + 8 * q][tx] = v;
  }
  __syncthreads();
#pragma unroll
  for (int q = 0; q < 4; ++q) {
    int jj = ty + 8 * q;
    int j = j0 + jj;
    if (j < D_IN) xT[(size_t)j * MB + b0 + tx] = f2bf(tile[tx][jj]);
  }
}

// ---- linear part + bias: out[b,:] = x[b,:] @ W1 + bias ----
__global__ __launch_bounds__(256) void init_out_kernel(const float* __restrict__ x,
                                                       const float* __restrict__ W,
                                                       const float* __restrict__ bias,
                                                       float* __restrict__ out) {
  int b = blockIdx.x;
  int t = threadIdx.x;
  __shared__ float part[OUTN];
  if (t < OUTN) part[t] = bias[t];
  __syncthreads();
  float acc[OUTN];
#pragma unroll
  for (int o = 0; o < OUTN; ++o) acc[o] = 0.f;
  for (int i = t; i < D_IN; i += 256) {
    float xv = x[(size_t)b * D_IN + i];
#pragma unroll
    for (int o = 0; o < OUTN; ++o) acc[o] += xv * W[i * OUTN + o];
  }
#pragma unroll
  for (int o = 0; o < OUTN; ++o) {
    float v = acc[o];
#pragma unroll
    for (int s = 32; s > 0; s >>= 1) v += __shfl_down(v, s);
    if ((t & 63) == 0) atomicAdd(&part[o], v);
  }
  __syncthreads();
  if (t < OUTN) out[(size_t)b * OUTN + t] = part[t];
}

// ---- main: Z-GEMM. Grid = 196 blocks x 512 thr; block owns i in
// [blk*4, blk*4+4), all 512 rows, all j. acc[b][o] accumulated directly. ----
template <int USE_WS>
__global__ __launch_bounds__(512, 1) void zgemm_kernel(const ushort_t* __restrict__ xb,
                                                       const ushort_t* __restrict__ xT,
                                                       const float* __restrict__ W2v,
                                                       float* __restrict__ dst) {
  __shared__ ushort_t xw[2][MB][40];          // x[b][j-window 32 + 8 pad] bf16, 80 KB
  __shared__ float xi[ISLAB][MB];             // x[b][i0..i0+3] f32, 8 KB
  __shared__ ushort_t Bl[2][16][40];          // W slice [o 16][k 32 + 8 pad] bf16, 2.5 KB
  const int tid = threadIdx.x;
  const int w = tid >> 6, l = tid & 63, lr = l & 15, lh = l >> 4;
  const int i0 = blockIdx.x * ISLAB;

  // ---- prologue ----
#pragma unroll
  for (int ii = 0; ii < ISLAB; ++ii) {
    ushort_t u = xT[(size_t)(i0 + ii) * MB + tid];
    xi[ii][tid] = __builtin_bit_cast(float, (uint_t)u << 16);
  }
  for (int t = tid; t < 640; t += 512) ((uint_t*)Bl)[t] = 0;  // zero (covers o=10..15 pad)
  {  // stage x-window jw=0
    const uint4* xsrc = (const uint4*)(xb + (size_t)tid * JP);
    uint4 a0 = xsrc[0], a1 = xsrc[1], a2 = xsrc[2], a3 = xsrc[3];
    uint4* xd = (uint4*)&xw[0][tid][0];
    xd[0] = a0; xd[1] = a1; xd[2] = a2; xd[3] = a3;
  }
  float rbB[4];                               // B prefetch regs, statically indexed
#pragma unroll
  for (int p = 0; p < 4; ++p)                 // loads for steps (jw=0, ii=p)
    rbB[p] = (tid < 320) ? W2v[((size_t)(i0 + p) * D_IN) * OUTN + tid] : 0.f;
  if (tid < 320) Bl[0][tid % 10][tid / 10] = f2bf(rbB[0]);   // write B(s=0)
  RAWBAR();

  f32x4 acc[4];
#pragma unroll
  for (int mf = 0; mf < 4; ++mf) acc[mf] = (f32x4){0.f, 0.f, 0.f, 0.f};

  float xjf[4][8];                            // x[b][j-window] as f32, per m-frag
  for (int jw = 0; jw < NJW; ++jw) {
    // xj for this window (amortized over ISLAB steps)
    const ushort_t* xwc = &xw[jw & 1][0][0];
#pragma unroll
    for (int mf = 0; mf < 4; ++mf) {
      int b = w * 64 + mf * 16 + lr;
      uint4 v = *(const uint4*)(xwc + (size_t)b * 40 + lh * 8);
      xjf[mf][0] = bfu_lo(v.x); xjf[mf][1] = bfu_hi(v.x);
      xjf[mf][2] = bfu_lo(v.y); xjf[mf][3] = bfu_hi(v.y);
      xjf[mf][4] = bfu_lo(v.z); xjf[mf][5] = bfu_hi(v.z);
      xjf[mf][6] = bfu_lo(v.w); xjf[mf][7] = bfu_hi(v.w);
    }
    // issue x-window prefetch for jw+1 (consumed at ii==3)
    uint4 r0, r1, r2, r3;
    if (jw + 1 < NJW) {
      const uint4* xs2 = (const uint4*)(xb + (size_t)tid * JP + (jw + 1) * 32);
      r0 = xs2[0]; r1 = xs2[1]; r2 = xs2[2]; r3 = xs2[3];
    }
#pragma unroll
    for (int ii = 0; ii < ISLAB; ++ii) {
      // issue B load for step (jw+1, ii) into rbB[ii] (4-step-deep pipeline)
      if (jw + 1 < NJW && tid < 320) {
        int lim = (jw + 1 == NJW - 1) ? 160 : 320;   // last window: j>=784 -> 0
        float nv = 0.f;
        if (tid < lim)
          nv = W2v[((size_t)(i0 + ii) * D_IN + (jw + 1) * 32) * OUTN + tid];
        rbB[ii] = nv;
      }
      // compute step s = (jw, ii): one 16x16x32 MFMA per m-frag
      const ushort_t* bb = &Bl[ii & 1][0][0];
      bf16x8 bfrag = *(const bf16x8*)(bb + lr * 40 + lh * 8);
#pragma unroll
      for (int mf = 0; mf < 4; ++mf) {
        float xiv = xi[ii][w * 64 + mf * 16 + lr];
        bf16x8 av;
#pragma unroll
        for (int e = 0; e < 8; ++e) av[e] = (__bf16)(xiv * xjf[mf][e]);
        acc[mf] = __builtin_amdgcn_mfma_f32_16x16x32_bf16(av, bfrag, acc[mf], 0, 0, 0);
      }
      // write B(s+1) into the other buffer (data loaded one full jw ago)
      if (!(jw == NJW - 1 && ii == ISLAB - 1) && tid < 320)
        Bl[(ii + 1) & 1][tid % 10][tid / 10] = f2bf(rbB[(ii + 1) & 3]);
      // write next x-window at last inner step
      if (ii == ISLAB - 1 && jw + 1 < NJW) {
        uint4* xd = (uint4*)&xw[(jw + 1) & 1][tid][0];
        xd[0] = r0; xd[1] = r1; xd[2] = r2; xd[3] = r3;
      }
      RAWBAR();
    }
  }

  // ---- epilogue: acc IS the quad partial over this block's i-slab ----
  // C/D layout: col = lane&15 (= o), row = (lane>>4)*4 + reg
#pragma unroll
  for (int mf = 0; mf < 4; ++mf) {
#pragma unroll
    for (int r = 0; r < 4; ++r) {
      int b = w * 64 + mf * 16 + lh * 4 + r;
      if (lr < OUTN) {
        if (USE_WS) dst[(size_t)blockIdx.x * (MB * OUTN) + b * OUTN + lr] = acc[mf][r];
        else atomicAdd(&dst[b * OUTN + lr], acc[mf][r]);
      }
    }
  }
}

// ---- reduce: out[i] += sum over 196 block partials ----
__global__ __launch_bounds__(256) void reduce_kernel(const float* __restrict__ ws,
                                                     float* __restrict__ out) {
  __shared__ float red[256];
  const int t = threadIdx.x;
  const int il = t & 31, slab = t >> 5;       // 8 slabs of blocks
  const int i = blockIdx.x * 32 + il;         // 160 blocks x 32 outputs
  float s = 0.f;
  for (int c = slab; c < NBLK; c += 8) s += ws[(size_t)c * (MB * OUTN) + i];
  red[t] = s;
  __syncthreads();
  if (t < 32) {
    float r = 0.f;
#pragma unroll
    for (int q = 0; q < 8; ++q) r += red[q * 32 + t];
    out[i] += r;
  }
}

extern "C" void kernel_launch(void* const* d_in, const int* in_sizes, int n_in,
                              void* d_out, int out_size, void* d_ws, size_t ws_size,
                              hipStream_t stream) {
  const float* x = (const float*)d_in[0];     // 512 x 784
  const float* W = (const float*)d_in[1];     // 615440 x 10
  const float* bias = (const float*)d_in[2];  // 10
  float* out = (float*)d_out;                 // 512 x 10 f32

  const size_t ws_part = (size_t)NBLK * MB * OUTN * 4;          // 4.01 MB
  const size_t xb_bytes = (size_t)MB * JP * 2;                  // 800 KB
  const size_t xt_bytes = (size_t)D_IN * MB * 2;                // 784 KB
  const size_t need_full = ws_part + xb_bytes + xt_bytes;

  if (ws_size >= need_full) {
    float* wsp = (float*)d_ws;
    ushort_t* xb = (ushort_t*)((char*)d_ws + ws_part);
    ushort_t* xT = (ushort_t*)((char*)d_ws + ws_part + xb_bytes);
    prep_kernel<<<dim3(NJW, 16), dim3(32, 8), 0, stream>>>(x, xb, xT);
    init_out_kernel<<<MB, 256, 0, stream>>>(x, W, bias, out);
    zgemm_kernel<1><<<NBLK, 512, 0, stream>>>(xb, xT, W + D_IN * OUTN, wsp);
    reduce_kernel<<<160, 256, 0, stream>>>(wsp, out);
  } else {
    ushort_t* xb = (ushort_t*)d_ws;
    ushort_t* xT = (ushort_t*)((char*)d_ws + xb_bytes);
    prep_kernel<<<dim3(NJW, 16), dim3(32, 8), 0, stream>>>(x, xb, xT);
    init_out_kernel<<<MB, 256, 0, stream>>>(x, W, bias, out);
    zgemm_kernel<0><<<NBLK, 512, 0, stream>>>(xb, xT, W + D_IN * OUTN, out);
  }
}

// Round 6
// 76.512 us; speedup vs baseline: 1.1782x; 1.0303x over previous
//
#include <hip/hip_runtime.h>

// out[b,o] = x@W1 + quad + bias,  quad[b,o] = sum_ij x[b,i] x[b,j] W2[i,j,o].
// Factored: quad[b,o] = sum_i x_i * t_i[b,o],  t_i[b,o] = sum_j x_j W2[i,j,o].
// t_i computed by MFMA with UNSCALED A = bf16(x) (shared across i); the x_i
// scale is applied to the f32 MFMA output (16 fma per i-slab per wave).
// Block = 256 rows x i-slab of 4; grid 392. Everything wave-private (own LDS
// region for x-window dbuf + B dbuf): ZERO barriers anywhere. B regs 4 steps
// deep, x-window 4 steps deep; W streamed contiguously, read once per b-half.

#define D_IN 784
#define NC10 7840        // 784*10, W2v row stride per i
#define JP 800           // j padded to 25*32
#define MB 512
#define OUTN 10
#define NJW 25
#define NSLAB 196
#define NBLK 392         // 196 slabs x 2 b-halves
#define XSTR 40          // ushorts per xw row (32 + 8 pad -> 80 B, 16B-aligned)
#define BSTR 40          // ushorts per Bl o-row
#define XWBUF (64 * XSTR)   // 2560 ushorts per x buffer
#define BLBUF (16 * BSTR)   // 640 ushorts per B buffer
#define WAVE_LDS (2 * XWBUF + 2 * BLBUF)   // 6400 ushorts = 12.8 KB / wave

typedef unsigned short ushort_t;
typedef unsigned int uint_t;
typedef __attribute__((ext_vector_type(4))) float f32x4;
typedef __attribute__((ext_vector_type(8))) __bf16 bf16x8;

__device__ __forceinline__ ushort_t f2bf(float f) {
  uint_t u = __builtin_bit_cast(uint_t, f);
  u += 0x7FFFu + ((u >> 16) & 1u);
  return (ushort_t)(u >> 16);
}

// ---- prep: x f32 [512][784] -> xb bf16 [512][800] (zero-padded cols) ----
__global__ __launch_bounds__(256) void prep_kernel(const float* __restrict__ x,
                                                   ushort_t* __restrict__ xb) {
  int t = blockIdx.x * 256 + threadIdx.x;     // 512*200 threads
  int b = t / 200;
  int c4 = (t - b * 200) * 4;
  ushort4 u;
  u.x = (c4 + 0 < D_IN) ? f2bf(x[(size_t)b * D_IN + c4 + 0]) : (ushort_t)0;
  u.y = (c4 + 1 < D_IN) ? f2bf(x[(size_t)b * D_IN + c4 + 1]) : (ushort_t)0;
  u.z = (c4 + 2 < D_IN) ? f2bf(x[(size_t)b * D_IN + c4 + 2]) : (ushort_t)0;
  u.w = (c4 + 3 < D_IN) ? f2bf(x[(size_t)b * D_IN + c4 + 3]) : (ushort_t)0;
  *(ushort4*)(xb + (size_t)b * JP + c4) = u;
}

// ---- linear part + bias: out[b,:] = x[b,:] @ W1 + bias ----
__global__ __launch_bounds__(256) void init_out_kernel(const float* __restrict__ x,
                                                       const float* __restrict__ W,
                                                       const float* __restrict__ bias,
                                                       float* __restrict__ out) {
  int b = blockIdx.x;
  int t = threadIdx.x;
  __shared__ float part[OUTN];
  if (t < OUTN) part[t] = bias[t];
  __syncthreads();
  float acc[OUTN];
#pragma unroll
  for (int o = 0; o < OUTN; ++o) acc[o] = 0.f;
  for (int i = t; i < D_IN; i += 256) {
    float xv = x[(size_t)b * D_IN + i];
#pragma unroll
    for (int o = 0; o < OUTN; ++o) acc[o] += xv * W[i * OUTN + o];
  }
#pragma unroll
  for (int o = 0; o < OUTN; ++o) {
    float v = acc[o];
#pragma unroll
    for (int s = 32; s > 0; s >>= 1) v += __shfl_down(v, s);
    if ((t & 63) == 0) atomicAdd(&part[o], v);
  }
  __syncthreads();
  if (t < OUTN) out[(size_t)b * OUTN + t] = part[t];
}

// ---- main: barrier-free factored quad kernel ----
template <int USE_WS>
__global__ __launch_bounds__(256, 3) void zgemm_kernel(const ushort_t* __restrict__ xb,
                                                       const float* __restrict__ W2v,
                                                       const float* __restrict__ x,
                                                       float* __restrict__ dst) {
  __shared__ ushort_t lds[4 * WAVE_LDS];      // 51.2 KB, wave-private regions
  const int tid = threadIdx.x;
  const int w = tid >> 6, l = tid & 63, lr = l & 15, lh = l >> 4;
  const int slab = blockIdx.x >> 1, bh = blockIdx.x & 1;
  const int i0 = slab * 4;
  const int b0 = bh * 256 + w * 64;           // wave's first global row

  ushort_t* xw = lds + w * WAVE_LDS;          // [2][64][XSTR]
  ushort_t* bl = xw + 2 * XWBUF;              // [2][16][BSTR]

  // zero both B buffers (covers o=10..15 pad and k>=16 tail)
  for (int u = l; u < 2 * BLBUF; u += 64) bl[u] = 0;

  // per-lane B LDS write offsets: m = q*64+l -> (o = m%10, k = m/10)
  int woff[5];
#pragma unroll
  for (int q = 0; q < 5; ++q) {
    int m = q * 64 + l;
    int k = (m * 205) >> 11;                  // exact m/10 for m<320
    woff[q] = (m - k * 10) * BSTR + k;
  }
  // x staging chunk coords: unit u = c*64+l -> row u>>2, 16B chunk u&3
  int xrow[4], xch[4];
#pragma unroll
  for (int c = 0; c < 4; ++c) { int u = c * 64 + l; xrow[c] = u >> 2; xch[c] = (u & 3) * 8; }

  const float* wbp[4];
#pragma unroll
  for (int ii = 0; ii < 4; ++ii) wbp[ii] = W2v + (size_t)(i0 + ii) * NC10 + l;

  float rb[4][5];                             // B prefetch, 4 steps deep (static idx)
  uint4 xr[4];

  // ---- prologue: B slices (jw=0, ii=0..3) + x window 0 ----
#pragma unroll
  for (int ii = 0; ii < 4; ++ii)
#pragma unroll
    for (int q = 0; q < 5; ++q) rb[ii][q] = wbp[ii][q * 64];
#pragma unroll
  for (int c = 0; c < 4; ++c)
    xr[c] = *(const uint4*)(xb + (size_t)(b0 + xrow[c]) * JP + xch[c]);
#pragma unroll
  for (int c = 0; c < 4; ++c)
    *(uint4*)(xw + xrow[c] * XSTR + xch[c]) = xr[c];
#pragma unroll
  for (int q = 0; q < 5; ++q) bl[woff[q]] = f2bf(rb[0][q]);   // step (0,0) -> buf 0

  f32x4 t[4][4];                              // [ii][mf], accumulated over ALL jw
#pragma unroll
  for (int ii = 0; ii < 4; ++ii)
#pragma unroll
    for (int mf = 0; mf < 4; ++mf) t[ii][mf] = (f32x4){0.f, 0.f, 0.f, 0.f};

  for (int jw = 0; jw < NJW; ++jw) {
    const int nxt = jw + 1;
    const bool has = nxt < NJW;
    // A-frags for this window (shared across all 4 ii steps)
    const ushort_t* xwc = xw + (jw & 1) * XWBUF;
    bf16x8 a[4];
#pragma unroll
    for (int mf = 0; mf < 4; ++mf)
      a[mf] = *(const bf16x8*)(xwc + (mf * 16 + lr) * XSTR + lh * 8);
    // issue x-window prefetch for jw+1 (consumed at end of this jw)
    if (has) {
#pragma unroll
      for (int c = 0; c < 4; ++c)
        xr[c] = *(const uint4*)(xb + (size_t)(b0 + xrow[c]) * JP + nxt * 32 + xch[c]);
    }
#pragma unroll
    for (int ii = 0; ii < 4; ++ii) {
      // issue B loads for (jw+1, ii): 4 steps ahead of their ds_write/use
      if (has) {
        const float* src = wbp[ii] + (size_t)nxt * 320;
        if (nxt == NJW - 1) {                 // last window: j>=784 -> zero
#pragma unroll
          for (int q = 0; q < 5; ++q) {
            int m = q * 64 + l;
            rb[ii][q] = (m < 160) ? src[q * 64] : 0.f;
          }
        } else {
#pragma unroll
          for (int q = 0; q < 5; ++q) rb[ii][q] = src[q * 64];
        }
      }
      // read this step's B frag (written last step into buf ii&1)
      bf16x8 bfrag = *(const bf16x8*)(bl + (ii & 1) * BLBUF + lr * BSTR + lh * 8);
      // write NEXT step's B slice into the other buffer (data loaded 4 steps ago)
      if (has || ii < 3) {
        ushort_t* bw = bl + ((ii + 1) & 1) * BLBUF;
#pragma unroll
        for (int q = 0; q < 5; ++q) bw[woff[q]] = f2bf(rb[(ii + 1) & 3][q]);
      }
#pragma unroll
      for (int mf = 0; mf < 4; ++mf)
        t[ii][mf] = __builtin_amdgcn_mfma_f32_16x16x32_bf16(a[mf], bfrag, t[ii][mf], 0, 0, 0);
    }
    // write next x-window (loads issued at top of this jw)
    if (has) {
      ushort_t* xd = xw + (nxt & 1) * XWBUF;
#pragma unroll
      for (int c = 0; c < 4; ++c)
        *(uint4*)(xd + xrow[c] * XSTR + xch[c]) = xr[c];
    }
  }

  // ---- epilogue: acc[b,o] = sum_ii x[b, i0+ii] * t[ii]  (f32, exact) ----
  // C/D: col = lane&15 (= o), row = (lane>>4)*4 + reg
#pragma unroll
  for (int mf = 0; mf < 4; ++mf) {
#pragma unroll
    for (int r = 0; r < 4; ++r) {
      int bloc = w * 64 + mf * 16 + lh * 4 + r;
      int b = bh * 256 + bloc;
      f32x4 xv = *(const f32x4*)(x + (size_t)b * D_IN + i0);   // 16B-aligned
      float v = xv[0] * t[0][mf][r] + xv[1] * t[1][mf][r]
              + xv[2] * t[2][mf][r] + xv[3] * t[3][mf][r];
      if (lr < OUTN) {
        if (USE_WS) dst[(size_t)blockIdx.x * 2560 + bloc * OUTN + lr] = v;
        else atomicAdd(&dst[(size_t)b * OUTN + lr], v);
      }
    }
  }
}

// ---- reduce: out[b,o] += sum over 196 slabs of the matching b-half partial ----
__global__ __launch_bounds__(256) void reduce_kernel(const float* __restrict__ ws,
                                                     float* __restrict__ out) {
  int i = blockIdx.x * 256 + threadIdx.x;     // 5120
  if (i >= MB * OUTN) return;
  int b = i / OUTN, o = i - b * OUTN;
  int bhh = b >> 8, bl = b & 255;
  const float* p = ws + (size_t)bhh * 2560 + bl * OUTN + o;
  float s0 = 0.f, s1 = 0.f, s2 = 0.f, s3 = 0.f;
#pragma unroll 1
  for (int c = 0; c + 4 <= NSLAB; c += 4) {
    s0 += p[(size_t)(c + 0) * 5120];
    s1 += p[(size_t)(c + 1) * 5120];
    s2 += p[(size_t)(c + 2) * 5120];
    s3 += p[(size_t)(c + 3) * 5120];
  }
  out[i] += (s0 + s1) + (s2 + s3);
}

extern "C" void kernel_launch(void* const* d_in, const int* in_sizes, int n_in,
                              void* d_out, int out_size, void* d_ws, size_t ws_size,
                              hipStream_t stream) {
  const float* x = (const float*)d_in[0];     // 512 x 784
  const float* W = (const float*)d_in[1];     // 615440 x 10
  const float* bias = (const float*)d_in[2];  // 10
  float* out = (float*)d_out;                 // 512 x 10 f32

  const size_t part_bytes = (size_t)NBLK * 2560 * 4;   // 4.01 MB
  const size_t xb_bytes = (size_t)MB * JP * 2;         // 800 KB

  if (ws_size >= part_bytes + xb_bytes) {
    float* wsp = (float*)d_ws;
    ushort_t* xb = (ushort_t*)((char*)d_ws + part_bytes);
    prep_kernel<<<400, 256, 0, stream>>>(x, xb);
    init_out_kernel<<<MB, 256, 0, stream>>>(x, W, bias, out);
    zgemm_kernel<1><<<NBLK, 256, 0, stream>>>(xb, W + D_IN * OUTN, x, wsp);
    reduce_kernel<<<20, 256, 0, stream>>>(wsp, out);
  } else {
    ushort_t* xb = (ushort_t*)d_ws;
    prep_kernel<<<400, 256, 0, stream>>>(x, xb);
    init_out_kernel<<<MB, 256, 0, stream>>>(x, W, bias, out);
    zgemm_kernel<0><<<NBLK, 256, 0, stream>>>(xb, W + D_IN * OUTN, x, out);
  }
}